// Round 2
// baseline (190.862 us; speedup 1.0000x reference)
//
#include <hip/hip_runtime.h>

// RoiCropper: image [B=8, D=128, H=128, W=128, C=1] f32, boxes [B, N=128, 3] i32
// out [B, N, 32, 32, 32, 1] f32
// out[b,n,z,y,x] = image[b, bz+z, by+y, bx+x] with starts clamped to [0, dim-32]
// (lax.dynamic_slice clamp semantics).

#define BB 8
#define NN 128
#define DD 128
#define HH 128
#define WW 128
#define RR 32

__global__ __launch_bounds__(256) void RoiCropper_79542794322056_kernel(
    const float* __restrict__ image,
    const int* __restrict__ boxes,
    float* __restrict__ out) {
  // One block per (b, n, z): grid = B*N*R = 8*128*32 = 32768 blocks.
  const int blk = blockIdx.x;
  const int z = blk & (RR - 1);
  const int bn = blk >> 5;            // b*N + n, 0..1023
  const int b = bn >> 7;              // bn / 128

  // Box start corner (block-uniform -> scalar loads).
  int bz = boxes[bn * 3 + 0];
  int by = boxes[bn * 3 + 1];
  int bx = boxes[bn * 3 + 2];
  // dynamic_slice clamps start so the slice stays in-bounds.
  bz = min(max(bz, 0), DD - RR);
  by = min(max(by, 0), HH - RR);
  bx = min(max(bx, 0), WW - RR);

  // Thread t covers (y = t/8, x = (t%8)*4 .. +3): 256 threads = 32x32 slab,
  // 4 floats (one float4 store) per thread.
  const int t = threadIdx.x;
  const int y = t >> 3;
  const int x4 = (t & 7) << 2;

  const size_t src_off =
      (((size_t)b * DD + (size_t)(bz + z)) * HH + (size_t)(by + y)) * WW +
      (size_t)(bx + x4);
  const float* src = image + src_off;

  float4 v;
  v.x = src[0];
  v.y = src[1];
  v.z = src[2];
  v.w = src[3];

  // Output: row base ((bn*R + z)*R + y)*R is a multiple of 32 floats -> the
  // float4 store at +x4 is 16B-aligned.
  const size_t dst_off =
      ((((size_t)bn * RR + z) * RR + y) * RR) + (size_t)x4;
  *reinterpret_cast<float4*>(out + dst_off) = v;
}

extern "C" void kernel_launch(void* const* d_in, const int* in_sizes, int n_in,
                              void* d_out, int out_size, void* d_ws, size_t ws_size,
                              hipStream_t stream) {
  const float* image = (const float*)d_in[0];
  const int* boxes = (const int*)d_in[1];
  float* out = (float*)d_out;

  const int grid = BB * NN * RR;  // 32768
  RoiCropper_79542794322056_kernel<<<grid, 256, 0, stream>>>(image, boxes, out);
}

// Round 4
// 186.150 us; speedup vs baseline: 1.0253x; 1.0253x over previous
//
#include <hip/hip_runtime.h>

// RoiCropper: image [B=8, D=128, H=128, W=128, C=1] f32, boxes [B, N=128, 3] i32
// out [B, N, 32, 32, 32, 1] f32
// out[b,n,z,y,x] = image[b, bz+z, by+y, bx+x] with starts clamped to [0, dim-32]
// (lax.dynamic_slice clamp semantics).
//
// Round 4: round-3 structure (grid = B*N*4, 8 z-slabs/thread, nontemporal
// stores) with the compile fix: __builtin_nontemporal_store needs a native
// clang vector type, not HIP's float4 class -> use ext_vector_type(4).

#define BB 8
#define NN 128
#define DD 128
#define HH 128
#define WW 128
#define RR 32
#define ZPB 8  // z-slabs per block

typedef float f32x4 __attribute__((ext_vector_type(4)));

__global__ __launch_bounds__(256) void RoiCropper_79542794322056_kernel(
    const float* __restrict__ image,
    const int* __restrict__ boxes,
    float* __restrict__ out) {
  const int blk = blockIdx.x;         // bn*4 + zq
  const int zq = blk & 3;             // which z-octant (8 slabs each)
  const int bn = blk >> 2;            // b*N + n, 0..1023
  const int b = bn >> 7;              // bn / 128

  // Box start corner (block-uniform -> scalar loads).
  int bz = boxes[bn * 3 + 0];
  int by = boxes[bn * 3 + 1];
  int bx = boxes[bn * 3 + 2];
  // dynamic_slice clamps start so the slice stays in-bounds.
  bz = min(max(bz, 0), DD - RR);
  by = min(max(by, 0), HH - RR);
  bx = min(max(bx, 0), WW - RR);

  // Thread t covers (y = t/8, x = (t%8)*4 .. +3) within each 32x32 z-slab.
  const int t = threadIdx.x;
  const int y = t >> 3;
  const int x4 = (t & 7) << 2;

  const int z0 = zq * ZPB;
  const float* src =
      image + (((size_t)b * DD + (size_t)(bz + z0)) * HH + (size_t)(by + y)) * WW +
      (size_t)(bx + x4);
  float* dst =
      out + ((((size_t)bn * RR + z0) * RR + y) * RR) + (size_t)x4;

#pragma unroll
  for (int zi = 0; zi < ZPB; ++zi) {
    const float* s = src + (size_t)zi * (HH * WW);
    f32x4 v;
    v.x = s[0];
    v.y = s[1];
    v.z = s[2];
    v.w = s[3];
    // Output row base is a multiple of 32 floats -> 16B-aligned at +x4.
    __builtin_nontemporal_store(v, reinterpret_cast<f32x4*>(dst + zi * (RR * RR)));
  }
}

extern "C" void kernel_launch(void* const* d_in, const int* in_sizes, int n_in,
                              void* d_out, int out_size, void* d_ws, size_t ws_size,
                              hipStream_t stream) {
  const float* image = (const float*)d_in[0];
  const int* boxes = (const int*)d_in[1];
  float* out = (float*)d_out;

  const int grid = BB * NN * (RR / ZPB);  // 4096
  RoiCropper_79542794322056_kernel<<<grid, 256, 0, stream>>>(image, boxes, out);
}